// Round 1
// baseline (337.319 us; speedup 1.0000x reference)
//
#include <hip/hip_runtime.h>
#include <hip/hip_bf16.h>

typedef _Float16 f16;
typedef _Float16 f16x8 __attribute__((ext_vector_type(8)));
typedef _Float16 f16x4 __attribute__((ext_vector_type(4)));
typedef float f32x4 __attribute__((ext_vector_type(4)));

constexpr int Bb = 8, Ss = 1024, Hh = 16, DH = 64, DM = 1024, N3 = 3072;
constexpr int Mm = Bb * Ss;  // 8192
constexpr float EPS = 1.1920929e-07f;

// ---------------- K0: RMS scales (one block per row) ----------------
__global__ void rms_kernel(const float* __restrict__ x, float* __restrict__ scales) {
    const int row = blockIdx.x;
    const int t = threadIdx.x;  // 256
    float4 v = *(const float4*)(x + (size_t)row * DM + t * 4);
    float s = v.x * v.x + v.y * v.y + v.z * v.z + v.w * v.w;
#pragma unroll
    for (int o = 32; o > 0; o >>= 1) s += __shfl_down(s, o, 64);
    __shared__ float red[4];
    if ((t & 63) == 0) red[t >> 6] = s;
    __syncthreads();
    if (t == 0) {
        float tot = red[0] + red[1] + red[2] + red[3];
        scales[row] = rsqrtf(tot * (1.0f / DM) + EPS);
    }
}

// ---------------- K1: weight casts fp32 -> fp16 ----------------
__global__ void castw_kernel(const float* __restrict__ Wqkv, const float* __restrict__ Wo,
                             f16* __restrict__ wq, f16* __restrict__ wo) {
    int i = blockIdx.x * 256 + threadIdx.x;
    const int n1 = N3 * DM;
    if (i < n1) {
        wq[i] = (f16)Wqkv[i];
    } else {
        int j = i - n1;
        if (j < DM * DM) wo[j] = (f16)Wo[j];
    }
}

// ---------------- K2: fused RMSNorm + QKV GEMM ----------------
// C[8192,3072] = (scale*x)[8192,1024] @ Wqkv^T, scatter-store as fp16 q/k/v
__launch_bounds__(256, 2)
__global__ void qkv_gemm(const float* __restrict__ x, const float* __restrict__ scales,
                         const f16* __restrict__ wq, const float* __restrict__ bqkv,
                         f16* __restrict__ qkv) {
    __shared__ f16 As[128][40];
    __shared__ f16 Bs[128][40];
    const int t = threadIdx.x;
    const int lane = t & 63, w = t >> 6;
    const int gm0 = blockIdx.y * 128, gn0 = blockIdx.x * 128;
    const int wm = (w >> 1) * 64, wn = (w & 1) * 64;
    f32x4 acc[4][4] = {};

    float sc[4];
#pragma unroll
    for (int it = 0; it < 4; ++it) sc[it] = scales[gm0 + it * 32 + (t >> 3)];

    for (int k0 = 0; k0 < DM; k0 += 32) {
        // stage A: 128x32 fp32 -> fp16 (scaled)
#pragma unroll
        for (int it = 0; it < 4; ++it) {
            int row = it * 32 + (t >> 3), colg = (t & 7) * 4;
            float4 v = *(const float4*)(x + (size_t)(gm0 + row) * DM + k0 + colg);
            f16x4 hv = {(f16)(v.x * sc[it]), (f16)(v.y * sc[it]),
                        (f16)(v.z * sc[it]), (f16)(v.w * sc[it])};
            *(f16x4*)&As[row][colg] = hv;
        }
        // stage B: 128x32 fp16
#pragma unroll
        for (int c0 = 0; c0 < 2; ++c0) {
            int c = c0 * 256 + t;
            int row = c >> 2, part = c & 3;
            *(f16x8*)&Bs[row][part * 8] =
                *(const f16x8*)(wq + (size_t)(gn0 + row) * DM + k0 + part * 8);
        }
        __syncthreads();
        f16x8 af[4], bf[4];
#pragma unroll
        for (int i = 0; i < 4; ++i)
            af[i] = *(const f16x8*)&As[wm + i * 16 + (lane & 15)][(lane >> 4) * 8];
#pragma unroll
        for (int i = 0; i < 4; ++i)
            bf[i] = *(const f16x8*)&Bs[wn + i * 16 + (lane & 15)][(lane >> 4) * 8];
#pragma unroll
        for (int mi = 0; mi < 4; ++mi)
#pragma unroll
            for (int ni = 0; ni < 4; ++ni)
                acc[mi][ni] = __builtin_amdgcn_mfma_f32_16x16x32_f16(af[mi], bf[ni], acc[mi][ni], 0, 0, 0);
        __syncthreads();
    }
    // epilogue: +bias, scatter into q/k/v [which][b*H+h][s][d]
#pragma unroll
    for (int mi = 0; mi < 4; ++mi) {
#pragma unroll
        for (int ni = 0; ni < 4; ++ni) {
            int jcol = gn0 + wn + ni * 16 + (lane & 15);
            float bb = bqkv[jcol];
            int h = jcol / 192, r = jcol % 192;
            int d = r / 3, which = r % 3;
#pragma unroll
            for (int jj = 0; jj < 4; ++jj) {
                int m = gm0 + wm + mi * 16 + (lane >> 4) * 4 + jj;
                int b = m >> 10, s = m & 1023;
                size_t dst = ((size_t)which * (Bb * Hh) + b * Hh + h) * (size_t)(Ss * DH) +
                             (size_t)s * DH + d;
                qkv[dst] = (f16)(acc[mi][ni][jj] + bb);
            }
        }
    }
}

// ---------------- K3a: per-column (over q) max & sumexp ----------------
// grid: x=16 (k-tile of 64), y=128 (b*h). Block loops q-tiles from diagonal down.
__launch_bounds__(256, 2)
__global__ void colstats_kernel(const f16* __restrict__ qkv, float* __restrict__ mbuf,
                                float* __restrict__ lbuf) {
    __shared__ f16 Ks[64][72];
    __shared__ f16 Qs[64][72];
    const int t = threadIdx.x, lane = t & 63, w = t >> 6;
    const int bh = blockIdx.y, kt = blockIdx.x;
    const size_t hs = (size_t)(Bb * Hh) * (Ss * DH);
    const f16* qb = qkv + (size_t)bh * (Ss * DH);
    const f16* kb = qb + hs;

#pragma unroll
    for (int c0 = 0; c0 < 2; ++c0) {
        int c = c0 * 256 + t;
        int row = c >> 3, part = c & 7;
        *(f16x8*)&Ks[row][part * 8] =
            *(const f16x8*)(kb + (size_t)(kt * 64 + row) * DH + part * 8);
    }
    __syncthreads();
    f16x8 b0 = *(const f16x8*)&Ks[w * 16 + (lane & 15)][(lane >> 4) * 8];
    f16x8 b1 = *(const f16x8*)&Ks[w * 16 + (lane & 15)][32 + (lane >> 4) * 8];
    float m_run = -INFINITY, l_run = 0.0f;
    const int kglob = kt * 64 + w * 16 + (lane & 15);

    for (int qt = kt; qt < 16; ++qt) {
        __syncthreads();
#pragma unroll
        for (int c0 = 0; c0 < 2; ++c0) {
            int c = c0 * 256 + t;
            int row = c >> 3, part = c & 7;
            *(f16x8*)&Qs[row][part * 8] =
                *(const f16x8*)(qb + (size_t)(qt * 64 + row) * DH + part * 8);
        }
        __syncthreads();
        bool diag = (qt == kt);
#pragma unroll
        for (int qs = 0; qs < 4; ++qs) {
            if (diag && (qs * 16 + 15) < w * 16) continue;  // fully masked subtile
            f16x8 a0 = *(const f16x8*)&Qs[qs * 16 + (lane & 15)][(lane >> 4) * 8];
            f16x8 a1 = *(const f16x8*)&Qs[qs * 16 + (lane & 15)][32 + (lane >> 4) * 8];
            f32x4 sf = {};
            sf = __builtin_amdgcn_mfma_f32_16x16x32_f16(a0, b0, sf, 0, 0, 0);
            sf = __builtin_amdgcn_mfma_f32_16x16x32_f16(a1, b1, sf, 0, 0, 0);
            float sv[4];
            float tmax = -INFINITY;
#pragma unroll
            for (int jj = 0; jj < 4; ++jj) {
                int q = qt * 64 + qs * 16 + (lane >> 4) * 4 + jj;
                bool valid = !diag || (q >= kglob);
                sv[jj] = valid ? sf[jj] : -INFINITY;
                tmax = fmaxf(tmax, sv[jj]);
            }
            tmax = fmaxf(tmax, __shfl_xor(tmax, 16, 64));
            tmax = fmaxf(tmax, __shfl_xor(tmax, 32, 64));
            float m_new = fmaxf(m_run, tmax);
            float ssum = 0.0f;
#pragma unroll
            for (int jj = 0; jj < 4; ++jj)
                ssum += (sv[jj] == -INFINITY) ? 0.0f : __expf(sv[jj] - m_new);
            ssum += __shfl_xor(ssum, 16, 64);
            ssum += __shfl_xor(ssum, 32, 64);
            float alpha = (m_run == -INFINITY) ? 0.0f : __expf(m_run - m_new);
            l_run = l_run * alpha + ssum;
            m_run = m_new;
        }
    }
    if ((lane >> 4) == 0) {
        mbuf[bh * Ss + kglob] = m_run;
        lbuf[bh * Ss + kglob] = l_run;
    }
}

// ---------------- K3b: z[q] = sum_k exp(S-m_k) * (v[k]/l_k) ----------------
// grid: x=16 (q-tile of 64), y=128 (b*h)
__launch_bounds__(256, 2)
__global__ void attnz_kernel(const f16* __restrict__ qkv, const float* __restrict__ mbuf,
                             const float* __restrict__ lbuf, f16* __restrict__ z) {
    __shared__ f16 Ks[64][72];
    __shared__ f16 Vt[64][72];  // [d][k] transposed, pre-scaled by 1/l
    __shared__ f16 Qs[64][72];
    __shared__ f16 Pl[4][16][72];
    const int t = threadIdx.x, lane = t & 63, w = t >> 6;
    const int bh = blockIdx.y, qt = blockIdx.x;
    const size_t hs = (size_t)(Bb * Hh) * (Ss * DH);
    const f16* qb = qkv + (size_t)bh * (Ss * DH);
    const f16* kb = qb + hs;
    const f16* vb = qb + 2 * hs;

#pragma unroll
    for (int c0 = 0; c0 < 2; ++c0) {
        int c = c0 * 256 + t;
        int row = c >> 3, part = c & 7;
        *(f16x8*)&Qs[row][part * 8] =
            *(const f16x8*)(qb + (size_t)(qt * 64 + row) * DH + part * 8);
    }
    __syncthreads();
    f16x8 aq0 = *(const f16x8*)&Qs[w * 16 + (lane & 15)][(lane >> 4) * 8];
    f16x8 aq1 = *(const f16x8*)&Qs[w * 16 + (lane & 15)][32 + (lane >> 4) * 8];
    f32x4 acc[4] = {};

    for (int kt = 0; kt <= qt; ++kt) {
        __syncthreads();
#pragma unroll
        for (int c0 = 0; c0 < 2; ++c0) {
            int c = c0 * 256 + t;
            int row = c >> 3, part = c & 7;
            *(f16x8*)&Ks[row][part * 8] =
                *(const f16x8*)(kb + (size_t)(kt * 64 + row) * DH + part * 8);
            f16x8 vv = *(const f16x8*)(vb + (size_t)(kt * 64 + row) * DH + part * 8);
            float invl = 1.0f / lbuf[bh * Ss + kt * 64 + row];
#pragma unroll
            for (int e = 0; e < 8; ++e)
                Vt[part * 8 + e][row] = (f16)((float)vv[e] * invl);
        }
        __syncthreads();
        // S = Q K^T (wave: 16 q-rows x 64 k-cols), P = exp(S - m_k) masked
#pragma unroll
        for (int ck = 0; ck < 4; ++ck) {
            if (kt == qt && ck * 16 > w * 16 + 15) {  // fully masked chunk
#pragma unroll
                for (int jj = 0; jj < 4; ++jj)
                    Pl[w][(lane >> 4) * 4 + jj][ck * 16 + (lane & 15)] = (f16)0.0f;
                continue;
            }
            f16x8 b0 = *(const f16x8*)&Ks[ck * 16 + (lane & 15)][(lane >> 4) * 8];
            f16x8 b1 = *(const f16x8*)&Ks[ck * 16 + (lane & 15)][32 + (lane >> 4) * 8];
            f32x4 sf = {};
            sf = __builtin_amdgcn_mfma_f32_16x16x32_f16(aq0, b0, sf, 0, 0, 0);
            sf = __builtin_amdgcn_mfma_f32_16x16x32_f16(aq1, b1, sf, 0, 0, 0);
            int kg = kt * 64 + ck * 16 + (lane & 15);
            float mk = mbuf[bh * Ss + kg];
#pragma unroll
            for (int jj = 0; jj < 4; ++jj) {
                int q = qt * 64 + w * 16 + (lane >> 4) * 4 + jj;
                float p = (kg <= q) ? __expf(sf[jj] - mk) : 0.0f;
                Pl[w][(lane >> 4) * 4 + jj][ck * 16 + (lane & 15)] = (f16)p;
            }
        }
        // PV: z[16q][64d] += P[16q][64k] @ V'[64k][64d]
        f16x8 pa0 = *(const f16x8*)&Pl[w][lane & 15][(lane >> 4) * 8];
        f16x8 pa1 = *(const f16x8*)&Pl[w][lane & 15][32 + (lane >> 4) * 8];
#pragma unroll
        for (int dk = 0; dk < 4; ++dk) {
            f16x8 bv0 = *(const f16x8*)&Vt[dk * 16 + (lane & 15)][(lane >> 4) * 8];
            f16x8 bv1 = *(const f16x8*)&Vt[dk * 16 + (lane & 15)][32 + (lane >> 4) * 8];
            acc[dk] = __builtin_amdgcn_mfma_f32_16x16x32_f16(pa0, bv0, acc[dk], 0, 0, 0);
            acc[dk] = __builtin_amdgcn_mfma_f32_16x16x32_f16(pa1, bv1, acc[dk], 0, 0, 0);
        }
    }
    // epilogue: z[b][s][h*64+d] fp16
    const int b = bh >> 4, h = bh & 15;
#pragma unroll
    for (int dk = 0; dk < 4; ++dk) {
#pragma unroll
        for (int jj = 0; jj < 4; ++jj) {
            int q = qt * 64 + w * 16 + (lane >> 4) * 4 + jj;
            int d = dk * 16 + (lane & 15);
            z[((size_t)(b * Ss + q)) * DM + h * DH + d] = (f16)acc[dk][jj];
        }
    }
}

// ---------------- K4: output projection ----------------
// out[8192,1024] = z[8192,1024] @ Wo^T + bo  (fp32 out)
__launch_bounds__(256, 2)
__global__ void out_gemm(const f16* __restrict__ z, const f16* __restrict__ wo,
                         const float* __restrict__ bo, float* __restrict__ out) {
    __shared__ f16 As[128][40];
    __shared__ f16 Bs[128][40];
    const int t = threadIdx.x;
    const int lane = t & 63, w = t >> 6;
    const int gm0 = blockIdx.y * 128, gn0 = blockIdx.x * 128;
    const int wm = (w >> 1) * 64, wn = (w & 1) * 64;
    f32x4 acc[4][4] = {};

    for (int k0 = 0; k0 < DM; k0 += 32) {
#pragma unroll
        for (int c0 = 0; c0 < 2; ++c0) {
            int c = c0 * 256 + t;
            int row = c >> 2, part = c & 3;
            *(f16x8*)&As[row][part * 8] =
                *(const f16x8*)(z + (size_t)(gm0 + row) * DM + k0 + part * 8);
            *(f16x8*)&Bs[row][part * 8] =
                *(const f16x8*)(wo + (size_t)(gn0 + row) * DM + k0 + part * 8);
        }
        __syncthreads();
        f16x8 af[4], bf[4];
#pragma unroll
        for (int i = 0; i < 4; ++i)
            af[i] = *(const f16x8*)&As[wm + i * 16 + (lane & 15)][(lane >> 4) * 8];
#pragma unroll
        for (int i = 0; i < 4; ++i)
            bf[i] = *(const f16x8*)&Bs[wn + i * 16 + (lane & 15)][(lane >> 4) * 8];
#pragma unroll
        for (int mi = 0; mi < 4; ++mi)
#pragma unroll
            for (int ni = 0; ni < 4; ++ni)
                acc[mi][ni] = __builtin_amdgcn_mfma_f32_16x16x32_f16(af[mi], bf[ni], acc[mi][ni], 0, 0, 0);
        __syncthreads();
    }
#pragma unroll
    for (int mi = 0; mi < 4; ++mi) {
#pragma unroll
        for (int ni = 0; ni < 4; ++ni) {
            int n = gn0 + wn + ni * 16 + (lane & 15);
            float bb = bo[n];
#pragma unroll
            for (int jj = 0; jj < 4; ++jj) {
                int m = gm0 + wm + mi * 16 + (lane >> 4) * 4 + jj;
                out[(size_t)m * DM + n] = acc[mi][ni][jj] + bb;
            }
        }
    }
}

extern "C" void kernel_launch(void* const* d_in, const int* in_sizes, int n_in,
                              void* d_out, int out_size, void* d_ws, size_t ws_size,
                              hipStream_t stream) {
    (void)in_sizes; (void)n_in; (void)out_size; (void)ws_size;
    const float* x    = (const float*)d_in[0];
    const float* Wqkv = (const float*)d_in[1];
    const float* bqkv = (const float*)d_in[2];
    const float* Wo   = (const float*)d_in[3];
    const float* bo   = (const float*)d_in[4];
    float* out = (float*)d_out;

    char* ws = (char*)d_ws;
    // workspace layout (bytes)
    float* scales = (float*)ws;                                   //    32768
    f16* wq   = (f16*)(ws + 32768);                               //  6291456
    f16* wo   = (f16*)(ws + 32768 + 6291456);                     //  2097152
    f16* qkv  = (f16*)(ws + 8421376);                             // 50331648 (3 x [128][1024][64])
    float* mbuf = (float*)(ws + 58753024);                        //   524288
    float* lbuf = (float*)(ws + 59277312);                        //   524288
    f16* z    = (f16*)(ws + 59801600);                            // 16777216  -> total ~73 MB

    rms_kernel<<<Mm, 256, 0, stream>>>(x, scales);
    castw_kernel<<<(N3 * DM + DM * DM) / 256, 256, 0, stream>>>(Wqkv, Wo, wq, wo);
    qkv_gemm<<<dim3(N3 / 128, Mm / 128), 256, 0, stream>>>(x, scales, wq, bqkv, qkv);
    colstats_kernel<<<dim3(16, Bb * Hh), 256, 0, stream>>>(qkv, mbuf, lbuf);
    attnz_kernel<<<dim3(16, Bb * Hh), 256, 0, stream>>>(qkv, mbuf, lbuf, z);
    out_gemm<<<dim3(DM / 128, Mm / 128), 256, 0, stream>>>(z, wo, bo, out);
}

// Round 2
// 248.633 us; speedup vs baseline: 1.3567x; 1.3567x over previous
//
#include <hip/hip_runtime.h>
#include <hip/hip_bf16.h>

typedef _Float16 f16;
typedef _Float16 f16x8 __attribute__((ext_vector_type(8)));
typedef _Float16 f16x4 __attribute__((ext_vector_type(4)));
typedef float f32x4 __attribute__((ext_vector_type(4)));

constexpr int Bb = 8, Ss = 1024, Hh = 16, DH = 64, DM = 1024, N3 = 3072;
constexpr int Mm = Bb * Ss;  // 8192
constexpr float EPS = 1.1920929e-07f;

// ---------------- K0: fused RMSNorm + cast -> xh (f16) ----------------
__global__ void rmscast_kernel(const float* __restrict__ x, f16* __restrict__ xh) {
    const int row = blockIdx.x;
    const int t = threadIdx.x;  // 256
    float4 v = *(const float4*)(x + (size_t)row * DM + t * 4);
    float s = v.x * v.x + v.y * v.y + v.z * v.z + v.w * v.w;
#pragma unroll
    for (int o = 32; o > 0; o >>= 1) s += __shfl_down(s, o, 64);
    __shared__ float red[4];
    if ((t & 63) == 0) red[t >> 6] = s;
    __syncthreads();
    float tot = red[0] + red[1] + red[2] + red[3];
    float sc = rsqrtf(tot * (1.0f / DM) + EPS);
    f16x4 hv = {(f16)(v.x * sc), (f16)(v.y * sc), (f16)(v.z * sc), (f16)(v.w * sc)};
    *(f16x4*)(xh + (size_t)row * DM + t * 4) = hv;
}

// ---------------- K1: weight casts fp32 -> fp16 ----------------
__global__ void castw_kernel(const float* __restrict__ Wqkv, const float* __restrict__ Wo,
                             f16* __restrict__ wq, f16* __restrict__ wo) {
    int i = blockIdx.x * 256 + threadIdx.x;
    const int n1 = N3 * DM;
    if (i < n1) {
        wq[i] = (f16)Wqkv[i];
    } else {
        int j = i - n1;
        if (j < DM * DM) wo[j] = (f16)Wo[j];
    }
}

// ---------------- K2: QKV GEMM on normed f16 x ----------------
// C[8192,3072] = xh @ Wqkv^T + b; scatter q,k -> [which][bh][s][d], v -> vT [bh][d][s]
__launch_bounds__(256, 2)
__global__ void qkv_gemm(const f16* __restrict__ xh, const f16* __restrict__ wq,
                         const float* __restrict__ bqkv, f16* __restrict__ qk,
                         f16* __restrict__ vT) {
    __shared__ f16 As[128][40];
    __shared__ f16 Bs[128][40];
    const int t = threadIdx.x;
    const int lane = t & 63, w = t >> 6;
    const int gm0 = blockIdx.y * 128, gn0 = blockIdx.x * 128;
    const int wm = (w >> 1) * 64, wn = (w & 1) * 64;
    f32x4 acc[4][4] = {};

    for (int k0 = 0; k0 < DM; k0 += 32) {
#pragma unroll
        for (int c0 = 0; c0 < 2; ++c0) {
            int c = c0 * 256 + t;
            int row = c >> 2, part = c & 3;
            *(f16x8*)&As[row][part * 8] =
                *(const f16x8*)(xh + (size_t)(gm0 + row) * DM + k0 + part * 8);
            *(f16x8*)&Bs[row][part * 8] =
                *(const f16x8*)(wq + (size_t)(gn0 + row) * DM + k0 + part * 8);
        }
        __syncthreads();
        f16x8 af[4], bf[4];
#pragma unroll
        for (int i = 0; i < 4; ++i)
            af[i] = *(const f16x8*)&As[wm + i * 16 + (lane & 15)][(lane >> 4) * 8];
#pragma unroll
        for (int i = 0; i < 4; ++i)
            bf[i] = *(const f16x8*)&Bs[wn + i * 16 + (lane & 15)][(lane >> 4) * 8];
#pragma unroll
        for (int mi = 0; mi < 4; ++mi)
#pragma unroll
            for (int ni = 0; ni < 4; ++ni)
                acc[mi][ni] = __builtin_amdgcn_mfma_f32_16x16x32_f16(af[mi], bf[ni], acc[mi][ni], 0, 0, 0);
        __syncthreads();
    }
    // epilogue: +bias, scatter
#pragma unroll
    for (int mi = 0; mi < 4; ++mi) {
#pragma unroll
        for (int ni = 0; ni < 4; ++ni) {
            int jcol = gn0 + wn + ni * 16 + (lane & 15);
            float bb = bqkv[jcol];
            int h = jcol / 192, r = jcol % 192;
            int d = r / 3, which = r % 3;
            int m0 = gm0 + wm + mi * 16 + (lane >> 4) * 4;
            int b = m0 >> 10, s0 = m0 & 1023;
            int bh = b * Hh + h;
            if (which == 2) {
                f16x4 pv = {(f16)(acc[mi][ni][0] + bb), (f16)(acc[mi][ni][1] + bb),
                            (f16)(acc[mi][ni][2] + bb), (f16)(acc[mi][ni][3] + bb)};
                *(f16x4*)(vT + ((size_t)bh * DH + d) * Ss + s0) = pv;
            } else {
                size_t base = ((size_t)which * (Bb * Hh) + bh) * (size_t)(Ss * DH) + (size_t)s0 * DH + d;
#pragma unroll
                for (int jj = 0; jj < 4; ++jj)
                    qk[base + (size_t)jj * DH] = (f16)(acc[mi][ni][jj] + bb);
            }
        }
    }
}

// ---------------- K3a: per-column (over q) stats c_k = m_k + log(l_k) ----------------
// grid: x=16 (k-tile of 64, longest first), y=128 (b*h)
__launch_bounds__(256, 2)
__global__ void colstats_kernel(const f16* __restrict__ qk, float* __restrict__ cbuf) {
    __shared__ f16 Ks[64][72];
    __shared__ f16 Qs[64][72];
    const int t = threadIdx.x, lane = t & 63, w = t >> 6;
    const int bh = blockIdx.y, kt = blockIdx.x;
    const size_t hs = (size_t)(Bb * Hh) * (Ss * DH);
    const f16* qb = qk + (size_t)bh * (Ss * DH);
    const f16* kb = qb + hs;

#pragma unroll
    for (int c0 = 0; c0 < 2; ++c0) {
        int c = c0 * 256 + t;
        int row = c >> 3, part = c & 7;
        *(f16x8*)&Ks[row][part * 8] =
            *(const f16x8*)(kb + (size_t)(kt * 64 + row) * DH + part * 8);
    }
    __syncthreads();
    f16x8 b0 = *(const f16x8*)&Ks[w * 16 + (lane & 15)][(lane >> 4) * 8];
    f16x8 b1 = *(const f16x8*)&Ks[w * 16 + (lane & 15)][32 + (lane >> 4) * 8];
    float m_run = -INFINITY, l_run = 0.0f;
    const int kglob = kt * 64 + w * 16 + (lane & 15);

    for (int qt = kt; qt < 16; ++qt) {
        __syncthreads();
#pragma unroll
        for (int c0 = 0; c0 < 2; ++c0) {
            int c = c0 * 256 + t;
            int row = c >> 3, part = c & 7;
            *(f16x8*)&Qs[row][part * 8] =
                *(const f16x8*)(qb + (size_t)(qt * 64 + row) * DH + part * 8);
        }
        __syncthreads();
        const bool diag = (qt == kt);
        float sv[16];
#pragma unroll
        for (int qs = 0; qs < 4; ++qs) {
            if (diag && (qs * 16 + 15) < w * 16) {
#pragma unroll
                for (int jj = 0; jj < 4; ++jj) sv[qs * 4 + jj] = -INFINITY;
                continue;
            }
            f16x8 a0 = *(const f16x8*)&Qs[qs * 16 + (lane & 15)][(lane >> 4) * 8];
            f16x8 a1 = *(const f16x8*)&Qs[qs * 16 + (lane & 15)][32 + (lane >> 4) * 8];
            f32x4 sf = {};
            sf = __builtin_amdgcn_mfma_f32_16x16x32_f16(a0, b0, sf, 0, 0, 0);
            sf = __builtin_amdgcn_mfma_f32_16x16x32_f16(a1, b1, sf, 0, 0, 0);
#pragma unroll
            for (int jj = 0; jj < 4; ++jj) {
                int q = qt * 64 + qs * 16 + (lane >> 4) * 4 + jj;
                sv[qs * 4 + jj] = (!diag || q >= kglob) ? sf[jj] : -INFINITY;
            }
        }
        float tmax = sv[0];
#pragma unroll
        for (int i = 1; i < 16; ++i) tmax = fmaxf(tmax, sv[i]);
        tmax = fmaxf(tmax, __shfl_xor(tmax, 16, 64));
        tmax = fmaxf(tmax, __shfl_xor(tmax, 32, 64));
        float m_new = fmaxf(m_run, tmax);
        float ssum = 0.0f;
#pragma unroll
        for (int i = 0; i < 16; ++i) ssum += __expf(sv[i] - m_new);
        ssum += __shfl_xor(ssum, 16, 64);
        ssum += __shfl_xor(ssum, 32, 64);
        l_run = l_run * __expf(m_run - m_new) + ssum;
        m_run = m_new;
    }
    if ((lane >> 4) == 0) cbuf[bh * Ss + kglob] = m_run + logf(l_run);
}

// ---------------- K3b: z[q] = sum_k exp(S[q,k]-c_k) * v[k] ----------------
// grid: x=16 (q-tile of 64, longest first), y=128 (b*h)
__launch_bounds__(256, 2)
__global__ void attnz_kernel(const f16* __restrict__ qk, const f16* __restrict__ vT,
                             const float* __restrict__ cbuf, f16* __restrict__ z) {
    __shared__ f16 Qs[64][72];
    __shared__ f16 Ks[64][72];
    __shared__ f16 Vt[64][72];  // [d][k-local], staged directly from global V^T
    __shared__ f16 Pl[4][16][72];
    const int t = threadIdx.x, lane = t & 63, w = t >> 6;
    const int bh = blockIdx.y, qt = 15 - blockIdx.x;  // longest first
    const size_t hs = (size_t)(Bb * Hh) * (Ss * DH);
    const f16* qb = qk + (size_t)bh * (Ss * DH);
    const f16* kb = qb + hs;
    const f16* vb = vT + (size_t)bh * (DH * Ss);

#pragma unroll
    for (int c0 = 0; c0 < 2; ++c0) {
        int c = c0 * 256 + t;
        int row = c >> 3, part = c & 7;
        *(f16x8*)&Qs[row][part * 8] =
            *(const f16x8*)(qb + (size_t)(qt * 64 + row) * DH + part * 8);
    }
    __syncthreads();
    f16x8 aq0 = *(const f16x8*)&Qs[w * 16 + (lane & 15)][(lane >> 4) * 8];
    f16x8 aq1 = *(const f16x8*)&Qs[w * 16 + (lane & 15)][32 + (lane >> 4) * 8];
    f32x4 acc[4] = {};

    for (int kt = 0; kt <= qt; ++kt) {
        __syncthreads();
#pragma unroll
        for (int c0 = 0; c0 < 2; ++c0) {
            int c = c0 * 256 + t;
            int row = c >> 3, part = c & 7;
            *(f16x8*)&Ks[row][part * 8] =
                *(const f16x8*)(kb + (size_t)(kt * 64 + row) * DH + part * 8);
            *(f16x8*)&Vt[row][part * 8] =
                *(const f16x8*)(vb + (size_t)row * Ss + kt * 64 + part * 8);
        }
        __syncthreads();
        const bool dtile = (kt == qt);
#pragma unroll
        for (int ck = 0; ck < 4; ++ck) {
            if (dtile && ck > w) {  // fully masked chunk
#pragma unroll
                for (int jj = 0; jj < 4; ++jj)
                    Pl[w][(lane >> 4) * 4 + jj][ck * 16 + (lane & 15)] = (f16)0.0f;
                continue;
            }
            f16x8 b0 = *(const f16x8*)&Ks[ck * 16 + (lane & 15)][(lane >> 4) * 8];
            f16x8 b1 = *(const f16x8*)&Ks[ck * 16 + (lane & 15)][32 + (lane >> 4) * 8];
            f32x4 sf = {};
            sf = __builtin_amdgcn_mfma_f32_16x16x32_f16(aq0, b0, sf, 0, 0, 0);
            sf = __builtin_amdgcn_mfma_f32_16x16x32_f16(aq1, b1, sf, 0, 0, 0);
            int kg = kt * 64 + ck * 16 + (lane & 15);
            float ckv = cbuf[bh * Ss + kg];
            const bool pmask = dtile && (ck == w);
#pragma unroll
            for (int jj = 0; jj < 4; ++jj) {
                int q = qt * 64 + w * 16 + (lane >> 4) * 4 + jj;
                float p = (!pmask || kg <= q) ? __expf(sf[jj] - ckv) : 0.0f;
                Pl[w][(lane >> 4) * 4 + jj][ck * 16 + (lane & 15)] = (f16)p;
            }
        }
        // PV: z[16q][64d] += P[16q][64k] @ Vt^T
        f16x8 pa0 = *(const f16x8*)&Pl[w][lane & 15][(lane >> 4) * 8];
        f16x8 pa1 = *(const f16x8*)&Pl[w][lane & 15][32 + (lane >> 4) * 8];
#pragma unroll
        for (int dk = 0; dk < 4; ++dk) {
            f16x8 bv0 = *(const f16x8*)&Vt[dk * 16 + (lane & 15)][(lane >> 4) * 8];
            f16x8 bv1 = *(const f16x8*)&Vt[dk * 16 + (lane & 15)][32 + (lane >> 4) * 8];
            acc[dk] = __builtin_amdgcn_mfma_f32_16x16x32_f16(pa0, bv0, acc[dk], 0, 0, 0);
            acc[dk] = __builtin_amdgcn_mfma_f32_16x16x32_f16(pa1, bv1, acc[dk], 0, 0, 0);
        }
    }
    // epilogue: z[b][s][h*64+d] f16
    const int b = bh >> 4, h = bh & 15;
#pragma unroll
    for (int dk = 0; dk < 4; ++dk) {
#pragma unroll
        for (int jj = 0; jj < 4; ++jj) {
            int q = qt * 64 + w * 16 + (lane >> 4) * 4 + jj;
            int d = dk * 16 + (lane & 15);
            z[((size_t)(b * Ss + q)) * DM + h * DH + d] = (f16)acc[dk][jj];
        }
    }
}

// ---------------- K4: output projection ----------------
__launch_bounds__(256, 2)
__global__ void out_gemm(const f16* __restrict__ z, const f16* __restrict__ wo,
                         const float* __restrict__ bo, float* __restrict__ out) {
    __shared__ f16 As[128][40];
    __shared__ f16 Bs[128][40];
    const int t = threadIdx.x;
    const int lane = t & 63, w = t >> 6;
    const int gm0 = blockIdx.y * 128, gn0 = blockIdx.x * 128;
    const int wm = (w >> 1) * 64, wn = (w & 1) * 64;
    f32x4 acc[4][4] = {};

    for (int k0 = 0; k0 < DM; k0 += 32) {
#pragma unroll
        for (int c0 = 0; c0 < 2; ++c0) {
            int c = c0 * 256 + t;
            int row = c >> 2, part = c & 3;
            *(f16x8*)&As[row][part * 8] =
                *(const f16x8*)(z + (size_t)(gm0 + row) * DM + k0 + part * 8);
            *(f16x8*)&Bs[row][part * 8] =
                *(const f16x8*)(wo + (size_t)(gn0 + row) * DM + k0 + part * 8);
        }
        __syncthreads();
        f16x8 af[4], bf[4];
#pragma unroll
        for (int i = 0; i < 4; ++i)
            af[i] = *(const f16x8*)&As[wm + i * 16 + (lane & 15)][(lane >> 4) * 8];
#pragma unroll
        for (int i = 0; i < 4; ++i)
            bf[i] = *(const f16x8*)&Bs[wn + i * 16 + (lane & 15)][(lane >> 4) * 8];
#pragma unroll
        for (int mi = 0; mi < 4; ++mi)
#pragma unroll
            for (int ni = 0; ni < 4; ++ni)
                acc[mi][ni] = __builtin_amdgcn_mfma_f32_16x16x32_f16(af[mi], bf[ni], acc[mi][ni], 0, 0, 0);
        __syncthreads();
    }
#pragma unroll
    for (int mi = 0; mi < 4; ++mi) {
#pragma unroll
        for (int ni = 0; ni < 4; ++ni) {
            int n = gn0 + wn + ni * 16 + (lane & 15);
            float bb = bo[n];
#pragma unroll
            for (int jj = 0; jj < 4; ++jj) {
                int m = gm0 + wm + mi * 16 + (lane >> 4) * 4 + jj;
                out[(size_t)m * DM + n] = acc[mi][ni][jj] + bb;
            }
        }
    }
}

extern "C" void kernel_launch(void* const* d_in, const int* in_sizes, int n_in,
                              void* d_out, int out_size, void* d_ws, size_t ws_size,
                              hipStream_t stream) {
    (void)in_sizes; (void)n_in; (void)out_size; (void)ws_size;
    const float* x    = (const float*)d_in[0];
    const float* Wqkv = (const float*)d_in[1];
    const float* bqkv = (const float*)d_in[2];
    const float* Wo   = (const float*)d_in[3];
    const float* bo   = (const float*)d_in[4];
    float* out = (float*)d_out;

    char* ws = (char*)d_ws;
    // workspace layout (bytes); z reuses xh's slot (xh dead after qkv_gemm)
    f16* xh   = (f16*)ws;                       // 16,777,216
    f16* z    = (f16*)ws;                       // reuse
    f16* wq   = (f16*)(ws + 16777216);          //  6,291,456
    f16* wo   = (f16*)(ws + 23068672);          //  2,097,152
    f16* qk   = (f16*)(ws + 25165824);          // 33,554,432 (2 x [128][1024][64])
    f16* vT   = (f16*)(ws + 58720256);          // 16,777,216 ([128][64][1024])
    float* cbuf = (float*)(ws + 75497472);      //    524,288  -> total ~76 MB

    rmscast_kernel<<<Mm, 256, 0, stream>>>(x, xh);
    castw_kernel<<<(N3 * DM + DM * DM) / 256, 256, 0, stream>>>(Wqkv, Wo, wq, wo);
    qkv_gemm<<<dim3(N3 / 128, Mm / 128), 256, 0, stream>>>(xh, wq, bqkv, qk, vT);
    colstats_kernel<<<dim3(16, Bb * Hh), 256, 0, stream>>>(qk, cbuf);
    attnz_kernel<<<dim3(16, Bb * Hh), 256, 0, stream>>>(qk, vT, cbuf, z);
    out_gemm<<<dim3(DM / 128, Mm / 128), 256, 0, stream>>>(z, wo, bo, out);
}

// Round 3
// 238.960 us; speedup vs baseline: 1.4116x; 1.0405x over previous
//
#include <hip/hip_runtime.h>
#include <hip/hip_bf16.h>

typedef _Float16 f16;
typedef _Float16 f16x8 __attribute__((ext_vector_type(8)));
typedef _Float16 f16x4 __attribute__((ext_vector_type(4)));
typedef float f32x4 __attribute__((ext_vector_type(4)));

constexpr int Bb = 8, Ss = 1024, Hh = 16, DH = 64, DM = 1024, N3 = 3072;
constexpr int Mm = Bb * Ss;  // 8192
constexpr float EPS = 1.1920929e-07f;

// async global->LDS, 16B per lane; LDS dest is wave-uniform base + lane*16
__device__ __forceinline__ void gll16(const f16* g, f16* l) {
    __builtin_amdgcn_global_load_lds(
        (__attribute__((address_space(1))) void*)(g),
        (__attribute__((address_space(3))) void*)(l), 16, 0, 0);
}

// ---------------- K0: fused RMSNorm + cast -> xh (f16) ----------------
__global__ void rmscast_kernel(const float* __restrict__ x, f16* __restrict__ xh) {
    const int row = blockIdx.x;
    const int t = threadIdx.x;  // 256
    float4 v = *(const float4*)(x + (size_t)row * DM + t * 4);
    float s = v.x * v.x + v.y * v.y + v.z * v.z + v.w * v.w;
#pragma unroll
    for (int o = 32; o > 0; o >>= 1) s += __shfl_down(s, o, 64);
    __shared__ float red[4];
    if ((t & 63) == 0) red[t >> 6] = s;
    __syncthreads();
    float tot = red[0] + red[1] + red[2] + red[3];
    float sc = rsqrtf(tot * (1.0f / DM) + EPS);
    f16x4 hv = {(f16)(v.x * sc), (f16)(v.y * sc), (f16)(v.z * sc), (f16)(v.w * sc)};
    *(f16x4*)(xh + (size_t)row * DM + t * 4) = hv;
}

// ---------------- K1: weight casts fp32 -> fp16 (vectorized) ----------------
__global__ void castw_kernel(const float* __restrict__ Wqkv, const float* __restrict__ Wo,
                             f16* __restrict__ wq, f16* __restrict__ wo) {
    int i = blockIdx.x * 256 + threadIdx.x;  // group of 4 elements
    const int n1 = (N3 * DM) / 4;
    if (i < n1) {
        float4 v = ((const float4*)Wqkv)[i];
        f16x4 h = {(f16)v.x, (f16)v.y, (f16)v.z, (f16)v.w};
        ((f16x4*)wq)[i] = h;
    } else {
        int j = i - n1;
        float4 v = ((const float4*)Wo)[j];
        f16x4 h = {(f16)v.x, (f16)v.y, (f16)v.z, (f16)v.w};
        ((f16x4*)wo)[j] = h;
    }
}

// ---------------- K2: QKV GEMM (m97 structure: gll16 + XOR swizzle) ----------------
// C[8192,3072] = xh @ Wqkv^T + b; scatter q,k -> [which][bh][s][d], v -> vT [bh][d][s]
__launch_bounds__(256, 2)
__global__ void qkv_gemm(const f16* __restrict__ xh, const f16* __restrict__ wq,
                         const float* __restrict__ bqkv, f16* __restrict__ qk,
                         f16* __restrict__ vT) {
    __shared__ __align__(16) f16 As[128 * 64];  // linear; content source-swizzled
    __shared__ __align__(16) f16 Bs[128 * 64];
    const int t = threadIdx.x, lane = t & 63, w = t >> 6;
    const int gm0 = blockIdx.y * 128, gn0 = blockIdx.x * 128;
    const int wm = (w >> 1) * 64, wn = (w & 1) * 64;
    const int srow = lane >> 3, sslot = (lane & 7) ^ srow;  // inverse-swizzled source granule
    const int r15 = lane & 15, cs = lane >> 4;

    const f16* Ag = xh + (size_t)(gm0 + srow) * DM + sslot * 8;
    const f16* Bg = wq + (size_t)(gn0 + srow) * DM + sslot * 8;

    int aoff[4][2], boff[4][2];  // swizzled ds_read offsets (f16 elements)
#pragma unroll
    for (int i = 0; i < 4; ++i) {
        int Ra = wm + i * 16 + r15;
        aoff[i][0] = Ra * 64 + ((cs ^ (Ra & 7)) * 8);
        aoff[i][1] = Ra * 64 + (((cs + 4) ^ (Ra & 7)) * 8);
        int Rb = wn + i * 16 + r15;
        boff[i][0] = Rb * 64 + ((cs ^ (Rb & 7)) * 8);
        boff[i][1] = Rb * 64 + (((cs + 4) ^ (Rb & 7)) * 8);
    }
    f32x4 acc[4][4] = {};

    for (int k0 = 0; k0 < DM; k0 += 64) {
        __syncthreads();
#pragma unroll
        for (int j = 0; j < 4; ++j) {
            int c = w * 4 + j;  // 8-row chunk, 16 chunks per tile
            gll16(Ag + (size_t)c * 8 * DM + k0, As + c * 512);
            gll16(Bg + (size_t)c * 8 * DM + k0, Bs + c * 512);
        }
        __syncthreads();
#pragma unroll
        for (int half = 0; half < 2; ++half) {
            f16x8 af[4], bf[4];
#pragma unroll
            for (int i = 0; i < 4; ++i) af[i] = *(const f16x8*)&As[aoff[i][half]];
#pragma unroll
            for (int i = 0; i < 4; ++i) bf[i] = *(const f16x8*)&Bs[boff[i][half]];
#pragma unroll
            for (int mi = 0; mi < 4; ++mi)
#pragma unroll
                for (int ni = 0; ni < 4; ++ni)
                    acc[mi][ni] = __builtin_amdgcn_mfma_f32_16x16x32_f16(af[mi], bf[ni], acc[mi][ni], 0, 0, 0);
        }
    }
    // epilogue: +bias, scatter
#pragma unroll
    for (int mi = 0; mi < 4; ++mi) {
#pragma unroll
        for (int ni = 0; ni < 4; ++ni) {
            int jcol = gn0 + wn + ni * 16 + r15;
            float bb = bqkv[jcol];
            int h = jcol / 192, r = jcol % 192;
            int d = r / 3, which = r % 3;
            int m0 = gm0 + wm + mi * 16 + cs * 4;
            int b = m0 >> 10, s0 = m0 & 1023;
            int bh = b * Hh + h;
            if (which == 2) {
                f16x4 pv = {(f16)(acc[mi][ni][0] + bb), (f16)(acc[mi][ni][1] + bb),
                            (f16)(acc[mi][ni][2] + bb), (f16)(acc[mi][ni][3] + bb)};
                *(f16x4*)(vT + ((size_t)bh * DH + d) * Ss + s0) = pv;
            } else {
                size_t base = ((size_t)which * (Bb * Hh) + bh) * (size_t)(Ss * DH) + (size_t)s0 * DH + d;
#pragma unroll
                for (int jj = 0; jj < 4; ++jj)
                    qk[base + (size_t)jj * DH] = (f16)(acc[mi][ni][jj] + bb);
            }
        }
    }
}

// ---------------- K3a: per-column (over q) stats c_k = m_k + log(l_k) ----------------
__launch_bounds__(256, 2)
__global__ void colstats_kernel(const f16* __restrict__ qk, float* __restrict__ cbuf) {
    __shared__ f16 Ks[64][72];
    __shared__ f16 Qs[64][72];
    const int t = threadIdx.x, lane = t & 63, w = t >> 6;
    const int bh = blockIdx.y, kt = blockIdx.x;
    const size_t hs = (size_t)(Bb * Hh) * (Ss * DH);
    const f16* qb = qk + (size_t)bh * (Ss * DH);
    const f16* kb = qb + hs;

#pragma unroll
    for (int c0 = 0; c0 < 2; ++c0) {
        int c = c0 * 256 + t;
        int row = c >> 3, part = c & 7;
        *(f16x8*)&Ks[row][part * 8] =
            *(const f16x8*)(kb + (size_t)(kt * 64 + row) * DH + part * 8);
    }
    __syncthreads();
    f16x8 b0 = *(const f16x8*)&Ks[w * 16 + (lane & 15)][(lane >> 4) * 8];
    f16x8 b1 = *(const f16x8*)&Ks[w * 16 + (lane & 15)][32 + (lane >> 4) * 8];
    float m_run = -INFINITY, l_run = 0.0f;
    const int kglob = kt * 64 + w * 16 + (lane & 15);

    for (int qt = kt; qt < 16; ++qt) {
        __syncthreads();
#pragma unroll
        for (int c0 = 0; c0 < 2; ++c0) {
            int c = c0 * 256 + t;
            int row = c >> 3, part = c & 7;
            *(f16x8*)&Qs[row][part * 8] =
                *(const f16x8*)(qb + (size_t)(qt * 64 + row) * DH + part * 8);
        }
        __syncthreads();
        const bool diag = (qt == kt);
        float sv[16];
#pragma unroll
        for (int qs = 0; qs < 4; ++qs) {
            if (diag && (qs * 16 + 15) < w * 16) {
#pragma unroll
                for (int jj = 0; jj < 4; ++jj) sv[qs * 4 + jj] = -INFINITY;
                continue;
            }
            f16x8 a0 = *(const f16x8*)&Qs[qs * 16 + (lane & 15)][(lane >> 4) * 8];
            f16x8 a1 = *(const f16x8*)&Qs[qs * 16 + (lane & 15)][32 + (lane >> 4) * 8];
            f32x4 sf = {};
            sf = __builtin_amdgcn_mfma_f32_16x16x32_f16(a0, b0, sf, 0, 0, 0);
            sf = __builtin_amdgcn_mfma_f32_16x16x32_f16(a1, b1, sf, 0, 0, 0);
#pragma unroll
            for (int jj = 0; jj < 4; ++jj) {
                int q = qt * 64 + qs * 16 + (lane >> 4) * 4 + jj;
                sv[qs * 4 + jj] = (!diag || q >= kglob) ? sf[jj] : -INFINITY;
            }
        }
        float tmax = sv[0];
#pragma unroll
        for (int i = 1; i < 16; ++i) tmax = fmaxf(tmax, sv[i]);
        tmax = fmaxf(tmax, __shfl_xor(tmax, 16, 64));
        tmax = fmaxf(tmax, __shfl_xor(tmax, 32, 64));
        float m_new = fmaxf(m_run, tmax);
        float ssum = 0.0f;
#pragma unroll
        for (int i = 0; i < 16; ++i) ssum += __expf(sv[i] - m_new);
        ssum += __shfl_xor(ssum, 16, 64);
        ssum += __shfl_xor(ssum, 32, 64);
        l_run = l_run * __expf(m_run - m_new) + ssum;
        m_run = m_new;
    }
    if ((lane >> 4) == 0) cbuf[bh * Ss + kglob] = m_run + logf(l_run);
}

// ---------------- K3b: z[q] = sum_k exp(S[q,k]-c_k) * v[k] ----------------
__launch_bounds__(256, 2)
__global__ void attnz_kernel(const f16* __restrict__ qk, const f16* __restrict__ vT,
                             const float* __restrict__ cbuf, f16* __restrict__ z) {
    __shared__ f16 Qs[64][72];
    __shared__ f16 Ks[64][72];
    __shared__ f16 Vt[64][72];
    __shared__ f16 Pl[4][16][72];
    const int t = threadIdx.x, lane = t & 63, w = t >> 6;
    const int bh = blockIdx.y, qt = 15 - blockIdx.x;  // longest first
    const size_t hs = (size_t)(Bb * Hh) * (Ss * DH);
    const f16* qb = qk + (size_t)bh * (Ss * DH);
    const f16* kb = qb + hs;
    const f16* vb = vT + (size_t)bh * (DH * Ss);

#pragma unroll
    for (int c0 = 0; c0 < 2; ++c0) {
        int c = c0 * 256 + t;
        int row = c >> 3, part = c & 7;
        *(f16x8*)&Qs[row][part * 8] =
            *(const f16x8*)(qb + (size_t)(qt * 64 + row) * DH + part * 8);
    }
    __syncthreads();
    f16x8 aq0 = *(const f16x8*)&Qs[w * 16 + (lane & 15)][(lane >> 4) * 8];
    f16x8 aq1 = *(const f16x8*)&Qs[w * 16 + (lane & 15)][32 + (lane >> 4) * 8];
    f32x4 acc[4] = {};

    for (int kt = 0; kt <= qt; ++kt) {
        __syncthreads();
#pragma unroll
        for (int c0 = 0; c0 < 2; ++c0) {
            int c = c0 * 256 + t;
            int row = c >> 3, part = c & 7;
            *(f16x8*)&Ks[row][part * 8] =
                *(const f16x8*)(kb + (size_t)(kt * 64 + row) * DH + part * 8);
            *(f16x8*)&Vt[row][part * 8] =
                *(const f16x8*)(vb + (size_t)row * Ss + kt * 64 + part * 8);
        }
        __syncthreads();
        const bool dtile = (kt == qt);
#pragma unroll
        for (int ck = 0; ck < 4; ++ck) {
            if (dtile && ck > w) {
#pragma unroll
                for (int jj = 0; jj < 4; ++jj)
                    Pl[w][(lane >> 4) * 4 + jj][ck * 16 + (lane & 15)] = (f16)0.0f;
                continue;
            }
            f16x8 b0 = *(const f16x8*)&Ks[ck * 16 + (lane & 15)][(lane >> 4) * 8];
            f16x8 b1 = *(const f16x8*)&Ks[ck * 16 + (lane & 15)][32 + (lane >> 4) * 8];
            f32x4 sf = {};
            sf = __builtin_amdgcn_mfma_f32_16x16x32_f16(aq0, b0, sf, 0, 0, 0);
            sf = __builtin_amdgcn_mfma_f32_16x16x32_f16(aq1, b1, sf, 0, 0, 0);
            int kg = kt * 64 + ck * 16 + (lane & 15);
            float ckv = cbuf[bh * Ss + kg];
            const bool pmask = dtile && (ck == w);
#pragma unroll
            for (int jj = 0; jj < 4; ++jj) {
                int q = qt * 64 + w * 16 + (lane >> 4) * 4 + jj;
                float p = (!pmask || kg <= q) ? __expf(sf[jj] - ckv) : 0.0f;
                Pl[w][(lane >> 4) * 4 + jj][ck * 16 + (lane & 15)] = (f16)p;
            }
        }
        f16x8 pa0 = *(const f16x8*)&Pl[w][lane & 15][(lane >> 4) * 8];
        f16x8 pa1 = *(const f16x8*)&Pl[w][lane & 15][32 + (lane >> 4) * 8];
#pragma unroll
        for (int dk = 0; dk < 4; ++dk) {
            f16x8 bv0 = *(const f16x8*)&Vt[dk * 16 + (lane & 15)][(lane >> 4) * 8];
            f16x8 bv1 = *(const f16x8*)&Vt[dk * 16 + (lane & 15)][32 + (lane >> 4) * 8];
            acc[dk] = __builtin_amdgcn_mfma_f32_16x16x32_f16(pa0, bv0, acc[dk], 0, 0, 0);
            acc[dk] = __builtin_amdgcn_mfma_f32_16x16x32_f16(pa1, bv1, acc[dk], 0, 0, 0);
        }
    }
    const int b = bh >> 4, h = bh & 15;
#pragma unroll
    for (int dk = 0; dk < 4; ++dk) {
#pragma unroll
        for (int jj = 0; jj < 4; ++jj) {
            int q = qt * 64 + w * 16 + (lane >> 4) * 4 + jj;
            int d = dk * 16 + (lane & 15);
            z[((size_t)(b * Ss + q)) * DM + h * DH + d] = (f16)acc[dk][jj];
        }
    }
}

// ---------------- K4: output projection (m97 structure) ----------------
__launch_bounds__(256, 2)
__global__ void out_gemm(const f16* __restrict__ z, const f16* __restrict__ wo,
                         const float* __restrict__ bo, float* __restrict__ out) {
    __shared__ __align__(16) f16 As[128 * 64];
    __shared__ __align__(16) f16 Bs[128 * 64];
    const int t = threadIdx.x, lane = t & 63, w = t >> 6;
    const int gm0 = blockIdx.y * 128, gn0 = blockIdx.x * 128;
    const int wm = (w >> 1) * 64, wn = (w & 1) * 64;
    const int srow = lane >> 3, sslot = (lane & 7) ^ srow;
    const int r15 = lane & 15, cs = lane >> 4;

    const f16* Ag = z + (size_t)(gm0 + srow) * DM + sslot * 8;
    const f16* Bg = wo + (size_t)(gn0 + srow) * DM + sslot * 8;

    int aoff[4][2], boff[4][2];
#pragma unroll
    for (int i = 0; i < 4; ++i) {
        int Ra = wm + i * 16 + r15;
        aoff[i][0] = Ra * 64 + ((cs ^ (Ra & 7)) * 8);
        aoff[i][1] = Ra * 64 + (((cs + 4) ^ (Ra & 7)) * 8);
        int Rb = wn + i * 16 + r15;
        boff[i][0] = Rb * 64 + ((cs ^ (Rb & 7)) * 8);
        boff[i][1] = Rb * 64 + (((cs + 4) ^ (Rb & 7)) * 8);
    }
    f32x4 acc[4][4] = {};

    for (int k0 = 0; k0 < DM; k0 += 64) {
        __syncthreads();
#pragma unroll
        for (int j = 0; j < 4; ++j) {
            int c = w * 4 + j;
            gll16(Ag + (size_t)c * 8 * DM + k0, As + c * 512);
            gll16(Bg + (size_t)c * 8 * DM + k0, Bs + c * 512);
        }
        __syncthreads();
#pragma unroll
        for (int half = 0; half < 2; ++half) {
            f16x8 af[4], bf[4];
#pragma unroll
            for (int i = 0; i < 4; ++i) af[i] = *(const f16x8*)&As[aoff[i][half]];
#pragma unroll
            for (int i = 0; i < 4; ++i) bf[i] = *(const f16x8*)&Bs[boff[i][half]];
#pragma unroll
            for (int mi = 0; mi < 4; ++mi)
#pragma unroll
                for (int ni = 0; ni < 4; ++ni)
                    acc[mi][ni] = __builtin_amdgcn_mfma_f32_16x16x32_f16(af[mi], bf[ni], acc[mi][ni], 0, 0, 0);
        }
    }
#pragma unroll
    for (int mi = 0; mi < 4; ++mi) {
#pragma unroll
        for (int ni = 0; ni < 4; ++ni) {
            int n = gn0 + wn + ni * 16 + r15;
            float bb = bo[n];
#pragma unroll
            for (int jj = 0; jj < 4; ++jj) {
                int m = gm0 + wm + mi * 16 + cs * 4 + jj;
                out[(size_t)m * DM + n] = acc[mi][ni][jj] + bb;
            }
        }
    }
}

extern "C" void kernel_launch(void* const* d_in, const int* in_sizes, int n_in,
                              void* d_out, int out_size, void* d_ws, size_t ws_size,
                              hipStream_t stream) {
    (void)in_sizes; (void)n_in; (void)out_size; (void)ws_size;
    const float* x    = (const float*)d_in[0];
    const float* Wqkv = (const float*)d_in[1];
    const float* bqkv = (const float*)d_in[2];
    const float* Wo   = (const float*)d_in[3];
    const float* bo   = (const float*)d_in[4];
    float* out = (float*)d_out;

    char* ws = (char*)d_ws;
    f16* xh   = (f16*)ws;                       // 16,777,216
    f16* z    = (f16*)ws;                       // reuse (xh dead after qkv_gemm)
    f16* wq   = (f16*)(ws + 16777216);          //  6,291,456
    f16* wo   = (f16*)(ws + 23068672);          //  2,097,152
    f16* qk   = (f16*)(ws + 25165824);          // 33,554,432
    f16* vT   = (f16*)(ws + 58720256);          // 16,777,216
    float* cbuf = (float*)(ws + 75497472);      //    524,288

    rmscast_kernel<<<Mm, 256, 0, stream>>>(x, xh);
    castw_kernel<<<(N3 * DM + DM * DM) / 1024, 256, 0, stream>>>(Wqkv, Wo, wq, wo);
    qkv_gemm<<<dim3(N3 / 128, Mm / 128), 256, 0, stream>>>(xh, wq, bqkv, qk, vT);
    colstats_kernel<<<dim3(16, Bb * Hh), 256, 0, stream>>>(qk, cbuf);
    attnz_kernel<<<dim3(16, Bb * Hh), 256, 0, stream>>>(qk, vT, cbuf, z);
    out_gemm<<<dim3(DM / 128, Mm / 128), 256, 0, stream>>>(z, wo, bo, out);
}